// Round 1
// baseline (9061.378 us; speedup 1.0000x reference)
//
#include <hip/hip_runtime.h>
#include <hip/hip_bf16.h>
#include <math.h>

// ---- dtype switches (flip if harness proves bf16 buffers) ----
typedef float in_t;
typedef float out_t;

__device__ __forceinline__ float ldi(const in_t* p, size_t i) { return (float)p[i]; }

#define DMODEL 192
#define NTOK   197
#define BT_    80
#define ROWS_  (BT_*NTOK)   // 15760

__device__ __forceinline__ float gelu_f(float v) {
  return 0.5f*v*(1.f + tanhf(0.7978845608028654f*(v + 0.044715f*v*v*v)));
}

// ================= GEMM: C = epi(A[M,K] @ W[K,N] + bias) =================
// EPI: 0 = bias only (bias may be null), 1 = bias+gelu, 2 = bias+residual(R)
template<int EPI>
__global__ __launch_bounds__(256)
void gemm_k(const float* __restrict__ A, const in_t* __restrict__ W,
            const in_t* __restrict__ bias, const float* __restrict__ R,
            float* __restrict__ C, int M, int N, int K)
{
  constexpr int BM=64, BN=64, BK=16;
  __shared__ float As[BK][BM+4];
  __shared__ float Ws[BK][BN+4];
  const int t = threadIdx.x;
  const int bm0 = blockIdx.y*BM, bn0 = blockIdx.x*BN;
  const int tm = (t>>4)*4;      // 0..60
  const int tn = (t&15)*4;      // 0..60
  const int la_m = t>>2;        // 0..63
  const int la_k = (t&3)*4;     // 0,4,8,12
  const int lw_k = t>>4;        // 0..15
  const int lw_n = (t&15)*4;    // 0..60
  float acc[4][4] = {};
  for (int k0 = 0; k0 < K; k0 += BK) {
    int gm = bm0 + la_m;
    float4 av = {0.f,0.f,0.f,0.f};
    if (gm < M) av = *(const float4*)(A + (size_t)gm*K + (size_t)(k0 + la_k));
    As[la_k+0][la_m] = av.x; As[la_k+1][la_m] = av.y;
    As[la_k+2][la_m] = av.z; As[la_k+3][la_m] = av.w;
    const in_t* wp = W + (size_t)(k0+lw_k)*N + (size_t)(bn0+lw_n);
    Ws[lw_k][lw_n+0] = ldi(wp,0); Ws[lw_k][lw_n+1] = ldi(wp,1);
    Ws[lw_k][lw_n+2] = ldi(wp,2); Ws[lw_k][lw_n+3] = ldi(wp,3);
    __syncthreads();
    #pragma unroll
    for (int kk=0; kk<BK; ++kk) {
      float4 a4 = *(const float4*)&As[kk][tm];
      float4 b4 = *(const float4*)&Ws[kk][tn];
      float ar[4] = {a4.x,a4.y,a4.z,a4.w};
      float br[4] = {b4.x,b4.y,b4.z,b4.w};
      #pragma unroll
      for (int ii=0; ii<4; ++ii)
        #pragma unroll
        for (int jj=0; jj<4; ++jj)
          acc[ii][jj] = fmaf(ar[ii], br[jj], acc[ii][jj]);
    }
    __syncthreads();
  }
  #pragma unroll
  for (int ii=0; ii<4; ++ii) {
    int gm = bm0 + tm + ii;
    if (gm >= M) continue;
    #pragma unroll
    for (int jj=0; jj<4; ++jj) {
      int gn = bn0 + tn + jj;
      float v = acc[ii][jj];
      if (bias) v += ldi(bias, gn);
      if (EPI==1) v = gelu_f(v);
      if (EPI==2) v += R[(size_t)gm*N + gn];
      C[(size_t)gm*N + gn] = v;
    }
  }
}

// ================= LayerNorm over width 192 =================
__global__ __launch_bounds__(256)
void ln_k(const float* __restrict__ x, const in_t* __restrict__ g, const in_t* __restrict__ b,
          float* __restrict__ o, int rows)
{
  int t = threadIdx.x, wave = t>>6, lane = t&63;
  int r = blockIdx.x*4 + wave;
  if (r >= rows) return;
  const float* xr = x + (size_t)r*DMODEL;
  float e0 = xr[lane], e1 = xr[lane+64], e2 = xr[lane+128];
  float s = e0+e1+e2;
  #pragma unroll
  for (int off=32; off; off>>=1) s += __shfl_xor(s, off);
  float mean = s / 192.f;
  float d0=e0-mean, d1=e1-mean, d2=e2-mean;
  float v = d0*d0+d1*d1+d2*d2;
  #pragma unroll
  for (int off=32; off; off>>=1) v += __shfl_xor(v, off);
  float rs = 1.f / sqrtf(v/192.f + 1e-6f);
  float* orow = o + (size_t)r*DMODEL;
  orow[lane]     = d0*rs*ldi(g,lane)     + ldi(b,lane);
  orow[lane+64]  = d1*rs*ldi(g,lane+64)  + ldi(b,lane+64);
  orow[lane+128] = d2*rs*ldi(g,lane+128) + ldi(b,lane+128);
}

// ================= Fused attention per (batch, head) =================
// qkv row layout: [q(h,d) | k(h,d) | v(h,d)], stride 3*heads*DH
// out row layout: heads*DH. attn0 (optional): softmax probs of query row 0.
constexpr int NPAD = 200;

template<int DH>
__global__ __launch_bounds__(256)
void attn_k(const float* __restrict__ qkv, float* __restrict__ out,
            float* __restrict__ attn0, int Nseq, int heads, float scale)
{
  __shared__ float Kt[DH*NPAD];   // transposed: Kt[d][j]
  __shared__ float Vs[NPAD*DH];   // Vs[j][d]
  __shared__ float Ps[4*NPAD];    // per-wave prob row
  __shared__ float Qs[4*DH];      // per-wave q row
  const int bh = blockIdx.x;
  const int b = bh / heads, h = bh % heads;
  const int stride = 3*heads*DH;
  const float* base = qkv + (size_t)b*Nseq*stride;
  const int qo = h*DH, ko = heads*DH + h*DH, vo = 2*heads*DH + h*DH;
  const int t = threadIdx.x, wave = t>>6, lane = t&63;

  for (int idx = t; idx < NPAD*DH; idx += 256) {
    int j = idx / DH, d = idx - j*DH;
    float kv = 0.f, vv = 0.f;
    if (j < Nseq) {
      kv = base[(size_t)j*stride + ko + d];
      vv = base[(size_t)j*stride + vo + d];
    }
    Kt[d*NPAD + j] = kv;
    Vs[j*DH + d]   = vv;
  }
  __syncthreads();

  const float NEG = -3.0e38f;
  const int iters = (Nseq + 3) >> 2;
  for (int it = 0; it < iters; ++it) {
    const int i = it*4 + wave;
    const bool active = (i < Nseq);
    if (active) {
      for (int d = lane; d < DH; d += 64)
        Qs[wave*DH + d] = base[(size_t)i*stride + qo + d];
    }
    __syncthreads();
    float inv = 0.f;
    if (active) {
      float s[4] = {0.f,0.f,0.f,0.f};
      #pragma unroll 8
      for (int d = 0; d < DH; ++d) {
        float qd = Qs[wave*DH + d];
        #pragma unroll
        for (int u = 0; u < 4; ++u) {
          int j = lane + u*64;
          if (j < NPAD) s[u] += qd * Kt[d*NPAD + j];
        }
      }
      float m = NEG;
      #pragma unroll
      for (int u = 0; u < 4; ++u) {
        int j = lane + u*64;
        s[u] = (j < Nseq) ? s[u]*scale : NEG;
        m = fmaxf(m, s[u]);
      }
      #pragma unroll
      for (int off=32; off; off>>=1) m = fmaxf(m, __shfl_xor(m, off));
      float p[4]; float sum = 0.f;
      #pragma unroll
      for (int u = 0; u < 4; ++u) {
        int j = lane + u*64;
        p[u] = (j < Nseq) ? expf(s[u] - m) : 0.f;
        sum += p[u];
      }
      #pragma unroll
      for (int off=32; off; off>>=1) sum += __shfl_xor(sum, off);
      inv = 1.f / sum;
      #pragma unroll
      for (int u = 0; u < 4; ++u) {
        int j = lane + u*64;
        if (j < NPAD) Ps[wave*NPAD + j] = p[u];
      }
      if (attn0 != nullptr && i == 0) {
        #pragma unroll
        for (int u = 0; u < 4; ++u) {
          int j = lane + u*64;
          if (j < Nseq) attn0[(size_t)bh*Nseq + j] = p[u]*inv;
        }
      }
    }
    __syncthreads();
    if (active) {
      constexpr int NPARTS = 64/DH;
      const int d = lane & (DH-1);
      const int part = lane / DH;
      float o = 0.f;
      for (int j4 = part; j4 < NPAD/4; j4 += NPARTS) {
        float4 p4 = *(const float4*)&Ps[wave*NPAD + j4*4];
        int jb = j4*4;
        o += p4.x * Vs[(jb+0)*DH + d];
        o += p4.y * Vs[(jb+1)*DH + d];
        o += p4.z * Vs[(jb+2)*DH + d];
        o += p4.w * Vs[(jb+3)*DH + d];
      }
      if (NPARTS == 2) o += __shfl_xor(o, 32);
      if (lane < DH)
        out[((size_t)b*Nseq + i)*(size_t)(heads*DH) + h*DH + d] = o*inv;
    }
    __syncthreads();
  }
}

// ================= patch extraction: x(16,5,3,224,224) -> A[15680,768] =================
__global__ void patchify_k(const in_t* __restrict__ x, float* __restrict__ A)
{
  int idx = blockIdx.x*256 + threadIdx.x;
  const int total = BT_*196*768;
  if (idx >= total) return;
  int kc = idx % 768;
  int m  = idx / 768;
  int p  = m % 196;
  int bt = m / 196;
  int c  = kc >> 8;          // 0..2
  int py = (kc >> 4) & 15;
  int px = kc & 15;
  int ph = p / 14, pw = p % 14;
  size_t src = (((size_t)bt*3 + c)*224 + (ph*16+py))*224 + (pw*16+px);
  A[idx] = ldi(x, src);
}

// ================= assemble tokens: cls + patches + pos =================
__global__ void assemble_k(const float* __restrict__ pt, const in_t* __restrict__ st,
                           const in_t* __restrict__ pe, float* __restrict__ X)
{
  int i = blockIdx.x*256 + threadIdx.x;
  const int total = BT_*NTOK*DMODEL;
  if (i >= total) return;
  int d  = i % DMODEL;
  int n  = (i / DMODEL) % NTOK;
  int bt = i / (DMODEL*NTOK);
  int tt = bt % 5;
  float base = (n == 0) ? ldi(st, d)
                        : pt[((size_t)bt*196 + (n-1))*DMODEL + d];
  X[i] = base + ldi(pe, ((size_t)tt*NTOK + n)*DMODEL + d);
}

// ================= ATS significance score =================
__global__ void score_k(const float* __restrict__ attn0, const float* __restrict__ qkv,
                        float* __restrict__ S)
{
  int b = blockIdx.x;
  int jj = threadIdx.x;
  if (jj >= 196) return;
  int j = jj + 1;
  float acc = 0.f;
  #pragma unroll
  for (int h = 0; h < 6; ++h) {
    float a0 = attn0[((size_t)b*6 + h)*NTOK + j];
    const float* v = qkv + ((size_t)b*NTOK + j)*576 + 384 + h*32;
    float ss = 0.f;
    #pragma unroll
    for (int d = 0; d < 32; ++d) ss += v[d]*v[d];
    acc += a0 * sqrtf(ss);
  }
  S[(size_t)b*196 + jj] = acc / 6.0f;
}

// ================= ATS sampling: cdf + searchsorted =================
__global__ void sample_k(const float* __restrict__ S, int* __restrict__ idxout)
{
  __shared__ float cdf[196];
  int b = blockIdx.x, t = threadIdx.x;
  if (t == 0) {
    float tot = 0.f;
    for (int k = 0; k < 196; ++k) tot += S[(size_t)b*196 + k];
    float denom = tot + 1e-8f;
    float run = 0.f;
    for (int k = 0; k < 196; ++k) { run += S[(size_t)b*196 + k] / denom; cdf[k] = run; }
    idxout[(size_t)b*NTOK] = 0;
  }
  __syncthreads();
  if (t < 196) {
    float u = ((float)t + 0.5f) / 196.0f;
    int cnt = 0;
    for (int k = 0; k < 196; ++k) cnt += (cdf[k] < u) ? 1 : 0;
    int c = cnt > 195 ? 195 : cnt;
    idxout[(size_t)b*NTOK + 1 + t] = c + 1;
  }
}

// ================= gather: Xo[n] = X[idx[n]] + P[idx[n]] =================
__global__ void gather_k(const float* __restrict__ X, const float* __restrict__ P,
                         const int* __restrict__ idx, float* __restrict__ Xo)
{
  int i = blockIdx.x*256 + threadIdx.x;
  const int total = BT_*NTOK*DMODEL;
  if (i >= total) return;
  int d  = i % DMODEL;
  int n  = (i / DMODEL) % NTOK;
  int bt = i / (DMODEL*NTOK);
  int src = idx[(size_t)bt*NTOK + n];
  size_t sr = ((size_t)bt*NTOK + src)*DMODEL + d;
  Xo[i] = X[sr] + P[sr];
}

// ================= build temporal sequence =================
__global__ void build_xc_k(const float* __restrict__ X, const in_t* __restrict__ tt,
                           float* __restrict__ xc)
{
  int i = blockIdx.x*256 + threadIdx.x;
  const int total = 16*6*DMODEL;
  if (i >= total) return;
  int d = i % DMODEL;
  int n = (i / DMODEL) % 6;
  int b = i / (DMODEL*6);
  xc[i] = (n == 0) ? ldi(tt, d)
                   : X[(((size_t)b*5 + (n-1))*NTOK + 0)*DMODEL + d];
}

// ================= maxpool + final LN + MLP head =================
__global__ __launch_bounds__(256)
void head_k(const float* __restrict__ xc, const in_t* __restrict__ fg, const in_t* __restrict__ fb,
            const in_t* __restrict__ w1, const in_t* __restrict__ b1,
            const in_t* __restrict__ w2, const in_t* __restrict__ b2,
            out_t* __restrict__ outp)
{
  __shared__ float fn[DMODEL];
  __shared__ float hid[64];
  __shared__ float mv[2];
  int b = blockIdx.x, t = threadIdx.x;
  if (t < DMODEL) {
    float m = xc[((size_t)b*6 + 0)*DMODEL + t];
    #pragma unroll
    for (int n = 1; n < 6; ++n) m = fmaxf(m, xc[((size_t)b*6 + n)*DMODEL + t]);
    fn[t] = m;
  }
  __syncthreads();
  if (t == 0) {
    float s = 0.f;
    for (int d = 0; d < DMODEL; ++d) s += fn[d];
    float mean = s / 192.f;
    float v = 0.f;
    for (int d = 0; d < DMODEL; ++d) { float dd = fn[d]-mean; v += dd*dd; }
    mv[0] = mean; mv[1] = 1.f / sqrtf(v/192.f + 1e-6f);
  }
  __syncthreads();
  if (t < DMODEL) fn[t] = (fn[t]-mv[0])*mv[1]*ldi(fg,t) + ldi(fb,t);
  __syncthreads();
  if (t < 64) {
    float a = ldi(b1, t);
    for (int d = 0; d < DMODEL; ++d) a += fn[d]*ldi(w1, (size_t)d*64 + t);
    hid[t] = fmaxf(a, 0.f);
  }
  __syncthreads();
  if (t < 2) {
    float a = ldi(b2, t);
    for (int j = 0; j < 64; ++j) a += hid[j]*ldi(w2, (size_t)j*2 + t);
    outp[(size_t)b*2 + t] = (out_t)a;
  }
}

// =========================================================================
extern "C" void kernel_launch(void* const* d_in, const int* in_sizes, int n_in,
                              void* d_out, int out_size, void* d_ws, size_t ws_size,
                              hipStream_t stream)
{
  if (n_in < 50) return;
  // ---- input pointers (setup_inputs dict order) ----
  const in_t* x_in     = (const in_t*)d_in[0];
  const in_t* patch_w  = (const in_t*)d_in[1];
  const in_t* patch_b  = (const in_t*)d_in[2];
  const in_t* pos_emb  = (const in_t*)d_in[3];
  const in_t* space_tk = (const in_t*)d_in[4];
  const in_t* temp_tk  = (const in_t*)d_in[5];
  const in_t* s_ln1_g = (const in_t*)d_in[6];  const in_t* s_ln1_b = (const in_t*)d_in[7];
  const in_t* s_qkv_w = (const in_t*)d_in[8];  const in_t* s_out_w = (const in_t*)d_in[9];
  const in_t* s_out_b = (const in_t*)d_in[10]; const in_t* s_ln2_g = (const in_t*)d_in[11];
  const in_t* s_ln2_b = (const in_t*)d_in[12]; const in_t* s_fc1_w = (const in_t*)d_in[13];
  const in_t* s_fc1_b = (const in_t*)d_in[14]; const in_t* s_fc2_w = (const in_t*)d_in[15];
  const in_t* s_fc2_b = (const in_t*)d_in[16]; const in_t* s_nrm_g = (const in_t*)d_in[17];
  const in_t* s_nrm_b = (const in_t*)d_in[18];
  const in_t* t_ln1_g = (const in_t*)d_in[19]; const in_t* t_ln1_b = (const in_t*)d_in[20];
  const in_t* t_qkv_w = (const in_t*)d_in[21]; const in_t* t_out_w = (const in_t*)d_in[22];
  const in_t* t_out_b = (const in_t*)d_in[23]; const in_t* t_ln2_g = (const in_t*)d_in[24];
  const in_t* t_ln2_b = (const in_t*)d_in[25]; const in_t* t_fc1_w = (const in_t*)d_in[26];
  const in_t* t_fc1_b = (const in_t*)d_in[27]; const in_t* t_fc2_w = (const in_t*)d_in[28];
  const in_t* t_fc2_b = (const in_t*)d_in[29]; const in_t* t_nrm_g = (const in_t*)d_in[30];
  const in_t* t_nrm_b = (const in_t*)d_in[31];
  const in_t* a_ln1_g = (const in_t*)d_in[32]; const in_t* a_ln1_b = (const in_t*)d_in[33];
  const in_t* a_qkv_w = (const in_t*)d_in[34]; const in_t* a_qkv_b = (const in_t*)d_in[35];
  const in_t* a_prj_w = (const in_t*)d_in[36]; const in_t* a_prj_b = (const in_t*)d_in[37];
  const in_t* a_ln2_g = (const in_t*)d_in[38]; const in_t* a_ln2_b = (const in_t*)d_in[39];
  const in_t* a_fc1_w = (const in_t*)d_in[40]; const in_t* a_fc1_b = (const in_t*)d_in[41];
  const in_t* a_fc2_w = (const in_t*)d_in[42]; const in_t* a_fc2_b = (const in_t*)d_in[43];
  const in_t* final_g = (const in_t*)d_in[44]; const in_t* final_b = (const in_t*)d_in[45];
  const in_t* h1_w = (const in_t*)d_in[46];    const in_t* h1_b = (const in_t*)d_in[47];
  const in_t* h2_w = (const in_t*)d_in[48];    const in_t* h2_b = (const in_t*)d_in[49];

  // ---- workspace partition (fp32 internal) ----
  float* ws = (float*)d_ws;
  size_t off = 0;
  auto alloc = [&](size_t nf) { size_t r = off; off += (nf + 63) & ~((size_t)63); return r; };
  size_t oX   = alloc((size_t)ROWS_*DMODEL);   // 15760*192
  size_t oX2  = alloc((size_t)ROWS_*DMODEL);
  size_t oH   = alloc((size_t)ROWS_*DMODEL);
  size_t oQKV = alloc((size_t)ROWS_*1152);
  size_t oY   = alloc((size_t)ROWS_*384);
  size_t oFF  = alloc((size_t)ROWS_*768);
  size_t oA0  = alloc((size_t)480*NTOK);
  size_t oSB  = alloc((size_t)BT_*196);
  size_t oXC  = alloc((size_t)16*6*DMODEL);
  size_t oIDX = alloc((size_t)BT_*NTOK);       // ints
  if (ws_size < off*sizeof(float)) return;     // workspace too small -> loud failure

  float* X   = ws + oX;
  float* X2  = ws + oX2;
  float* H   = ws + oH;
  float* QKV = ws + oQKV;
  float* Y   = ws + oY;
  float* FF  = ws + oFF;
  float* A0  = ws + oA0;
  float* SB  = ws + oSB;
  float* XC  = ws + oXC;
  int*   IDX = (int*)(ws + oIDX);

  auto gemm = [&](int epi, const float* A, const in_t* W, const in_t* bias,
                  const float* R, float* C, int M, int N, int K) {
    dim3 grid(N/64, (M+63)/64);
    if (epi == 0)      hipLaunchKernelGGL(gemm_k<0>, grid, dim3(256), 0, stream, A, W, bias, R, C, M, N, K);
    else if (epi == 1) hipLaunchKernelGGL(gemm_k<1>, grid, dim3(256), 0, stream, A, W, bias, R, C, M, N, K);
    else               hipLaunchKernelGGL(gemm_k<2>, grid, dim3(256), 0, stream, A, W, bias, R, C, M, N, K);
  };
  auto ln = [&](const float* xi, const in_t* g, const in_t* b, float* o, int rows) {
    hipLaunchKernelGGL(ln_k, dim3((rows+3)/4), dim3(256), 0, stream, xi, g, b, o, rows);
  };

  // ---- 1. patch embedding ----
  {
    int total = BT_*196*768;
    hipLaunchKernelGGL(patchify_k, dim3((total+255)/256), dim3(256), 0, stream, x_in, FF);
    gemm(0, FF, patch_w, patch_b, nullptr, Y, BT_*196, DMODEL, 768);
    int tot2 = BT_*NTOK*DMODEL;
    hipLaunchKernelGGL(assemble_k, dim3((tot2+255)/256), dim3(256), 0, stream, Y, space_tk, pos_emb, X);
  }

  const float sc64 = 0.125f;                   // 64^-0.5
  const float sc32 = 0.17677669529663687f;     // 32^-0.5

  // ---- 2. spatial transformer (2 layers, heads=6, dh=64) ----
  for (int i = 0; i < 2; ++i) {
    ln(X, s_ln1_g + (size_t)i*192, s_ln1_b + (size_t)i*192, H, ROWS_);
    gemm(0, H, s_qkv_w + (size_t)i*192*1152, nullptr, nullptr, QKV, ROWS_, 1152, 192);
    hipLaunchKernelGGL(attn_k<64>, dim3(BT_*6), dim3(256), 0, stream, QKV, Y, (float*)nullptr, NTOK, 6, sc64);
    gemm(2, Y, s_out_w + (size_t)i*384*192, s_out_b + (size_t)i*192, X, X, ROWS_, 192, 384);
    ln(X, s_ln2_g + (size_t)i*192, s_ln2_b + (size_t)i*192, H, ROWS_);
    gemm(1, H, s_fc1_w + (size_t)i*192*768, s_fc1_b + (size_t)i*768, nullptr, FF, ROWS_, 768, 192);
    gemm(2, FF, s_fc2_w + (size_t)i*768*192, s_fc2_b + (size_t)i*192, X, X, ROWS_, 192, 768);
  }
  ln(X, s_nrm_g, s_nrm_b, X, ROWS_);

  // ---- 3. ATS blocks (12 layers, heads=6, dh=32) ----
  float* xa = X; float* xb = X2;
  for (int i = 0; i < 12; ++i) {
    ln(xa, a_ln1_g + (size_t)i*192, a_ln1_b + (size_t)i*192, H, ROWS_);
    gemm(0, H, a_qkv_w + (size_t)i*192*576, a_qkv_b + (size_t)i*576, nullptr, QKV, ROWS_, 576, 192);
    hipLaunchKernelGGL(attn_k<32>, dim3(BT_*6), dim3(256), 0, stream, QKV, Y, A0, NTOK, 6, sc32);
    gemm(0, Y, a_prj_w + (size_t)i*192*192, a_prj_b + (size_t)i*192, nullptr, H, ROWS_, 192, 192);
    hipLaunchKernelGGL(score_k, dim3(BT_), dim3(256), 0, stream, A0, QKV, SB);
    hipLaunchKernelGGL(sample_k, dim3(BT_), dim3(256), 0, stream, SB, IDX);
    {
      int tot = BT_*NTOK*DMODEL;
      hipLaunchKernelGGL(gather_k, dim3((tot+255)/256), dim3(256), 0, stream, xa, H, IDX, xb);
    }
    ln(xb, a_ln2_g + (size_t)i*192, a_ln2_b + (size_t)i*192, H, ROWS_);
    gemm(1, H, a_fc1_w + (size_t)i*192*768, a_fc1_b + (size_t)i*768, nullptr, FF, ROWS_, 768, 192);
    gemm(2, FF, a_fc2_w + (size_t)i*768*192, a_fc2_b + (size_t)i*192, xb, xb, ROWS_, 192, 768);
    float* tmp = xa; xa = xb; xb = tmp;
  }

  // ---- 4. temporal transformer (3 layers on [16,6,192]) ----
  {
    int tot = 16*6*DMODEL;
    hipLaunchKernelGGL(build_xc_k, dim3((tot+255)/256), dim3(256), 0, stream, xa, temp_tk, XC);
  }
  const int MT = 16*6;
  for (int i = 0; i < 3; ++i) {
    ln(XC, t_ln1_g + (size_t)i*192, t_ln1_b + (size_t)i*192, H, MT);
    gemm(0, H, t_qkv_w + (size_t)i*192*1152, nullptr, nullptr, QKV, MT, 1152, 192);
    hipLaunchKernelGGL(attn_k<64>, dim3(16*6), dim3(256), 0, stream, QKV, Y, (float*)nullptr, 6, 6, sc64);
    gemm(2, Y, t_out_w + (size_t)i*384*192, t_out_b + (size_t)i*192, XC, XC, MT, 192, 384);
    ln(XC, t_ln2_g + (size_t)i*192, t_ln2_b + (size_t)i*192, H, MT);
    gemm(1, H, t_fc1_w + (size_t)i*192*768, t_fc1_b + (size_t)i*768, nullptr, FF, MT, 768, 192);
    gemm(2, FF, t_fc2_w + (size_t)i*768*192, t_fc2_b + (size_t)i*192, XC, XC, MT, 192, 768);
  }
  ln(XC, t_nrm_g, t_nrm_b, XC, MT);

  // ---- 5. maxpool + final LN + head ----
  hipLaunchKernelGGL(head_k, dim3(16), dim3(256), 0, stream, XC, final_g, final_b,
                     h1_w, h1_b, h2_w, h2_b, (out_t*)d_out);
}

// Round 2
// 6532.429 us; speedup vs baseline: 1.3871x; 1.3871x over previous
//
#include <hip/hip_runtime.h>
#include <hip/hip_bf16.h>
#include <math.h>

// ---- dtype switches ----
typedef float in_t;
typedef float out_t;

__device__ __forceinline__ float ldi(const in_t* p, size_t i) { return (float)p[i]; }

#define DMODEL 192
#define NTOK   197
#define BT_    80
#define ROWS_  (BT_*NTOK)   // 15760

__device__ __forceinline__ float gelu_f(float v) {
  return 0.5f*v*(1.f + tanhf(0.7978845608028654f*(v + 0.044715f*v*v*v)));
}

// ================= GEMM: C = epi(A[M,K] @ W[K,N] + bias) =================
// EPI: 0 = bias only (bias may be null), 1 = bias+gelu, 2 = bias+residual(R)
template<int EPI>
__global__ __launch_bounds__(256)
void gemm_k(const float* __restrict__ A, const in_t* __restrict__ W,
            const in_t* __restrict__ bias, const float* __restrict__ R,
            float* __restrict__ C, int M, int N, int K)
{
  constexpr int BM=64, BN=64, BK=16;
  __shared__ float As[BK][BM+4];
  __shared__ float Ws[BK][BN+4];
  const int t = threadIdx.x;
  const int bm0 = blockIdx.y*BM, bn0 = blockIdx.x*BN;
  const int tm = (t>>4)*4;      // 0..60
  const int tn = (t&15)*4;      // 0..60
  const int la_m = t>>2;        // 0..63
  const int la_k = (t&3)*4;     // 0,4,8,12
  const int lw_k = t>>4;        // 0..15
  const int lw_n = (t&15)*4;    // 0..60
  float acc[4][4] = {};
  for (int k0 = 0; k0 < K; k0 += BK) {
    int gm = bm0 + la_m;
    float4 av = {0.f,0.f,0.f,0.f};
    if (gm < M) av = *(const float4*)(A + (size_t)gm*K + (size_t)(k0 + la_k));
    As[la_k+0][la_m] = av.x; As[la_k+1][la_m] = av.y;
    As[la_k+2][la_m] = av.z; As[la_k+3][la_m] = av.w;
    const in_t* wp = W + (size_t)(k0+lw_k)*N + (size_t)(bn0+lw_n);
    Ws[lw_k][lw_n+0] = ldi(wp,0); Ws[lw_k][lw_n+1] = ldi(wp,1);
    Ws[lw_k][lw_n+2] = ldi(wp,2); Ws[lw_k][lw_n+3] = ldi(wp,3);
    __syncthreads();
    #pragma unroll
    for (int kk=0; kk<BK; ++kk) {
      float4 a4 = *(const float4*)&As[kk][tm];
      float4 b4 = *(const float4*)&Ws[kk][tn];
      float ar[4] = {a4.x,a4.y,a4.z,a4.w};
      float br[4] = {b4.x,b4.y,b4.z,b4.w};
      #pragma unroll
      for (int ii=0; ii<4; ++ii)
        #pragma unroll
        for (int jj=0; jj<4; ++jj)
          acc[ii][jj] = fmaf(ar[ii], br[jj], acc[ii][jj]);
    }
    __syncthreads();
  }
  #pragma unroll
  for (int ii=0; ii<4; ++ii) {
    int gm = bm0 + tm + ii;
    if (gm >= M) continue;
    #pragma unroll
    for (int jj=0; jj<4; ++jj) {
      int gn = bn0 + tn + jj;
      float v = acc[ii][jj];
      if (bias) v += ldi(bias, gn);
      if (EPI==1) v = gelu_f(v);
      if (EPI==2) v += R[(size_t)gm*N + gn];
      C[(size_t)gm*N + gn] = v;
    }
  }
}

// ================= LayerNorm over width 192 =================
__global__ __launch_bounds__(256)
void ln_k(const float* __restrict__ x, const in_t* __restrict__ g, const in_t* __restrict__ b,
          float* __restrict__ o, int rows)
{
  int t = threadIdx.x, wave = t>>6, lane = t&63;
  int r = blockIdx.x*4 + wave;
  if (r >= rows) return;
  const float* xr = x + (size_t)r*DMODEL;
  float e0 = xr[lane], e1 = xr[lane+64], e2 = xr[lane+128];
  float s = e0+e1+e2;
  #pragma unroll
  for (int off=32; off; off>>=1) s += __shfl_xor(s, off);
  float mean = s / 192.f;
  float d0=e0-mean, d1=e1-mean, d2=e2-mean;
  float v = d0*d0+d1*d1+d2*d2;
  #pragma unroll
  for (int off=32; off; off>>=1) v += __shfl_xor(v, off);
  float rs = 1.f / sqrtf(v/192.f + 1e-6f);
  float* orow = o + (size_t)r*DMODEL;
  orow[lane]     = d0*rs*ldi(g,lane)     + ldi(b,lane);
  orow[lane+64]  = d1*rs*ldi(g,lane+64)  + ldi(b,lane+64);
  orow[lane+128] = d2*rs*ldi(g,lane+128) + ldi(b,lane+128);
}

// ================= Fused attention v2 =================
// One block per (b,h). W waves; each wave independently processes 8-query
// chunks. K staged transposed in LDS (one barrier); Q-tile and P-rows are
// per-wave LDS regions (wave-local, in-order LDS pipe -> no barriers).
// V read directly from global (L1/L2-hot). attn0 (optional): row-0 probs.
template<int DH, int W>
__global__ __launch_bounds__(W*64)
void attn2_k(const float* __restrict__ qkv, float* __restrict__ out,
             float* __restrict__ attn0, int Nseq, int heads, float scale)
{
  constexpr int QT = 8;
  constexpr int KTS = 204;            // Kt row stride (floats), 16B-aligned
  constexpr int NPARTS = 64 / DH;
  __shared__ float Kt[DH * KTS];
  __shared__ float Qt[W][DH][12];     // [d][q] per wave, stride 12 (16B-aligned)
  __shared__ float Ps[W][QT][200];

  const int bh = blockIdx.x;
  const int b = bh / heads, h = bh % heads;
  const int stride = 3 * heads * DH;
  const float* __restrict__ base = qkv + (size_t)b * Nseq * stride;
  const int qo = h * DH, ko = heads * DH + h * DH, vo = 2 * heads * DH + h * DH;
  const int t = threadIdx.x, w = t >> 6, lane = t & 63;

  // ---- stage K transposed: Kt[d][j] ----
  for (int idx = t; idx < Nseq * DH; idx += W * 64) {
    int j = idx / DH, d0 = idx - j * DH;
    Kt[d0 * KTS + j] = base[(size_t)j * stride + ko + d0];
  }
  __syncthreads();

  const int d = lane & (DH - 1);
  const int part = (DH == 64) ? 0 : (lane >> 5);
  const int nchunks = (Nseq + QT - 1) / QT;
  const int jcmax = (Nseq + 3) >> 2;
  const float NEG = -3.0e38f;
  const float4* Kt4 = (const float4*)Kt;

  for (int ic = w; ic < nchunks; ic += W) {
    const int i0 = ic * QT;
    // stage this wave's 8 q rows: Qt[w][d][q]
    if (part == 0) {
      #pragma unroll
      for (int q = 0; q < QT; ++q) {
        int i = i0 + q;
        Qt[w][d][q] = (i < Nseq) ? base[(size_t)i * stride + qo + d] : 0.f;
      }
    }
    // ---- QK^T: lane l covers j = 4l..4l+3 ----
    float s[QT][4];
    #pragma unroll
    for (int q = 0; q < QT; ++q)
      #pragma unroll
      for (int u = 0; u < 4; ++u) s[q][u] = 0.f;
    #pragma unroll 4
    for (int dd = 0; dd < DH; ++dd) {
      float4 kv = (lane <= 50) ? Kt4[dd * (KTS/4) + lane] : float4{0.f,0.f,0.f,0.f};
      float4 qA = *(const float4*)&Qt[w][dd][0];
      float4 qB = *(const float4*)&Qt[w][dd][4];
      float qv[8] = {qA.x, qA.y, qA.z, qA.w, qB.x, qB.y, qB.z, qB.w};
      float kr[4] = {kv.x, kv.y, kv.z, kv.w};
      #pragma unroll
      for (int q = 0; q < QT; ++q)
        #pragma unroll
        for (int u = 0; u < 4; ++u)
          s[q][u] = fmaf(qv[q], kr[u], s[q][u]);
    }
    // ---- softmax per row ----
    float inv[QT];
    #pragma unroll
    for (int q = 0; q < QT; ++q) {
      float mx = NEG;
      #pragma unroll
      for (int u = 0; u < 4; ++u) {
        int j = 4*lane + u;
        s[q][u] = (j < Nseq) ? s[q][u]*scale : NEG;
        mx = fmaxf(mx, s[q][u]);
      }
      #pragma unroll
      for (int off = 32; off; off >>= 1) mx = fmaxf(mx, __shfl_xor(mx, off));
      float p[4]; float sum = 0.f;
      #pragma unroll
      for (int u = 0; u < 4; ++u) { p[u] = expf(s[q][u] - mx); sum += p[u]; }
      #pragma unroll
      for (int off = 32; off; off >>= 1) sum += __shfl_xor(sum, off);
      inv[q] = 1.f / sum;
      if (lane < 50)
        *(float4*)&Ps[w][q][4*lane] = make_float4(p[0], p[1], p[2], p[3]);
      if (attn0 != nullptr && i0 == 0 && q == 0) {
        #pragma unroll
        for (int u = 0; u < 4; ++u) {
          int j = 4*lane + u;
          if (j < Nseq) attn0[(size_t)bh*Nseq + j] = p[u]*inv[0];
        }
      }
    }
    // ---- PV: lane = d (+part for DH=32), V from global ----
    float o[QT];
    #pragma unroll
    for (int q = 0; q < QT; ++q) o[q] = 0.f;
    const float* __restrict__ Vg = base + vo;
    for (int jc = part; jc < jcmax; jc += NPARTS) {
      int jb = 4*jc;
      float v0 = (jb+0 < Nseq) ? Vg[(size_t)(jb+0)*stride + d] : 0.f;
      float v1 = (jb+1 < Nseq) ? Vg[(size_t)(jb+1)*stride + d] : 0.f;
      float v2 = (jb+2 < Nseq) ? Vg[(size_t)(jb+2)*stride + d] : 0.f;
      float v3 = (jb+3 < Nseq) ? Vg[(size_t)(jb+3)*stride + d] : 0.f;
      #pragma unroll
      for (int q = 0; q < QT; ++q) {
        float4 pq = *(const float4*)&Ps[w][q][jb];
        o[q] = fmaf(pq.w, v3, fmaf(pq.z, v2, fmaf(pq.y, v1, fmaf(pq.x, v0, o[q]))));
      }
    }
    if (NPARTS == 2) {
      #pragma unroll
      for (int q = 0; q < QT; ++q) o[q] += __shfl_xor(o[q], 32);
    }
    #pragma unroll
    for (int q = 0; q < QT; ++q) {
      int i = i0 + q;
      if (i < Nseq && part == 0)
        out[((size_t)b*Nseq + i)*(size_t)(heads*DH) + h*DH + d] = o[q]*inv[q];
    }
  }
}

// ================= patch extraction: x(16,5,3,224,224) -> A[15680,768] =================
__global__ void patchify_k(const in_t* __restrict__ x, float* __restrict__ A)
{
  int idx = blockIdx.x*256 + threadIdx.x;
  const int total = BT_*196*768;
  if (idx >= total) return;
  int kc = idx % 768;
  int m  = idx / 768;
  int p  = m % 196;
  int bt = m / 196;
  int c  = kc >> 8;          // 0..2
  int py = (kc >> 4) & 15;
  int px = kc & 15;
  int ph = p / 14, pw = p % 14;
  size_t src = (((size_t)bt*3 + c)*224 + (ph*16+py))*224 + (pw*16+px);
  A[idx] = ldi(x, src);
}

// ================= assemble tokens: cls + patches + pos =================
__global__ void assemble_k(const float* __restrict__ pt, const in_t* __restrict__ st,
                           const in_t* __restrict__ pe, float* __restrict__ X)
{
  int i = blockIdx.x*256 + threadIdx.x;
  const int total = BT_*NTOK*DMODEL;
  if (i >= total) return;
  int d  = i % DMODEL;
  int n  = (i / DMODEL) % NTOK;
  int bt = i / (DMODEL*NTOK);
  int tt = bt % 5;
  float base = (n == 0) ? ldi(st, d)
                        : pt[((size_t)bt*196 + (n-1))*DMODEL + d];
  X[i] = base + ldi(pe, ((size_t)tt*NTOK + n)*DMODEL + d);
}

// ================= ATS significance score =================
__global__ void score_k(const float* __restrict__ attn0, const float* __restrict__ qkv,
                        float* __restrict__ S)
{
  int b = blockIdx.x;
  int jj = threadIdx.x;
  if (jj >= 196) return;
  int j = jj + 1;
  float acc = 0.f;
  #pragma unroll
  for (int h = 0; h < 6; ++h) {
    float a0 = attn0[((size_t)b*6 + h)*NTOK + j];
    const float* v = qkv + ((size_t)b*NTOK + j)*576 + 384 + h*32;
    float ss = 0.f;
    #pragma unroll
    for (int d = 0; d < 32; ++d) ss += v[d]*v[d];
    acc += a0 * sqrtf(ss);
  }
  S[(size_t)b*196 + jj] = acc / 6.0f;
}

// ================= ATS sampling: cdf + searchsorted =================
__global__ void sample_k(const float* __restrict__ S, int* __restrict__ idxout)
{
  __shared__ float cdf[196];
  int b = blockIdx.x, t = threadIdx.x;
  if (t == 0) {
    float tot = 0.f;
    for (int k = 0; k < 196; ++k) tot += S[(size_t)b*196 + k];
    float denom = tot + 1e-8f;
    float run = 0.f;
    for (int k = 0; k < 196; ++k) { run += S[(size_t)b*196 + k] / denom; cdf[k] = run; }
    idxout[(size_t)b*NTOK] = 0;
  }
  __syncthreads();
  if (t < 196) {
    float u = ((float)t + 0.5f) / 196.0f;
    int cnt = 0;
    for (int k = 0; k < 196; ++k) cnt += (cdf[k] < u) ? 1 : 0;
    int c = cnt > 195 ? 195 : cnt;
    idxout[(size_t)b*NTOK + 1 + t] = c + 1;
  }
}

// ================= gather: Xo[n] = X[idx[n]] + P[idx[n]] =================
__global__ void gather_k(const float* __restrict__ X, const float* __restrict__ P,
                         const int* __restrict__ idx, float* __restrict__ Xo)
{
  int i = blockIdx.x*256 + threadIdx.x;
  const int total = BT_*NTOK*DMODEL;
  if (i >= total) return;
  int d  = i % DMODEL;
  int n  = (i / DMODEL) % NTOK;
  int bt = i / (DMODEL*NTOK);
  int src = idx[(size_t)bt*NTOK + n];
  size_t sr = ((size_t)bt*NTOK + src)*DMODEL + d;
  Xo[i] = X[sr] + P[sr];
}

// ================= build temporal sequence =================
__global__ void build_xc_k(const float* __restrict__ X, const in_t* __restrict__ tt,
                           float* __restrict__ xc)
{
  int i = blockIdx.x*256 + threadIdx.x;
  const int total = 16*6*DMODEL;
  if (i >= total) return;
  int d = i % DMODEL;
  int n = (i / DMODEL) % 6;
  int b = i / (DMODEL*6);
  xc[i] = (n == 0) ? ldi(tt, d)
                   : X[(((size_t)b*5 + (n-1))*NTOK + 0)*DMODEL + d];
}

// ================= maxpool + final LN + MLP head =================
__global__ __launch_bounds__(256)
void head_k(const float* __restrict__ xc, const in_t* __restrict__ fg, const in_t* __restrict__ fb,
            const in_t* __restrict__ w1, const in_t* __restrict__ b1,
            const in_t* __restrict__ w2, const in_t* __restrict__ b2,
            out_t* __restrict__ outp)
{
  __shared__ float fn[DMODEL];
  __shared__ float hid[64];
  __shared__ float mv[2];
  int b = blockIdx.x, t = threadIdx.x;
  if (t < DMODEL) {
    float m = xc[((size_t)b*6 + 0)*DMODEL + t];
    #pragma unroll
    for (int n = 1; n < 6; ++n) m = fmaxf(m, xc[((size_t)b*6 + n)*DMODEL + t]);
    fn[t] = m;
  }
  __syncthreads();
  if (t == 0) {
    float s = 0.f;
    for (int d = 0; d < DMODEL; ++d) s += fn[d];
    float mean = s / 192.f;
    float v = 0.f;
    for (int d = 0; d < DMODEL; ++d) { float dd = fn[d]-mean; v += dd*dd; }
    mv[0] = mean; mv[1] = 1.f / sqrtf(v/192.f + 1e-6f);
  }
  __syncthreads();
  if (t < DMODEL) fn[t] = (fn[t]-mv[0])*mv[1]*ldi(fg,t) + ldi(fb,t);
  __syncthreads();
  if (t < 64) {
    float a = ldi(b1, t);
    for (int d = 0; d < DMODEL; ++d) a += fn[d]*ldi(w1, (size_t)d*64 + t);
    hid[t] = fmaxf(a, 0.f);
  }
  __syncthreads();
  if (t < 2) {
    float a = ldi(b2, t);
    for (int j = 0; j < 64; ++j) a += hid[j]*ldi(w2, (size_t)j*2 + t);
    outp[(size_t)b*2 + t] = (out_t)a;
  }
}

// =========================================================================
extern "C" void kernel_launch(void* const* d_in, const int* in_sizes, int n_in,
                              void* d_out, int out_size, void* d_ws, size_t ws_size,
                              hipStream_t stream)
{
  if (n_in < 50) return;
  // ---- input pointers (setup_inputs dict order) ----
  const in_t* x_in     = (const in_t*)d_in[0];
  const in_t* patch_w  = (const in_t*)d_in[1];
  const in_t* patch_b  = (const in_t*)d_in[2];
  const in_t* pos_emb  = (const in_t*)d_in[3];
  const in_t* space_tk = (const in_t*)d_in[4];
  const in_t* temp_tk  = (const in_t*)d_in[5];
  const in_t* s_ln1_g = (const in_t*)d_in[6];  const in_t* s_ln1_b = (const in_t*)d_in[7];
  const in_t* s_qkv_w = (const in_t*)d_in[8];  const in_t* s_out_w = (const in_t*)d_in[9];
  const in_t* s_out_b = (const in_t*)d_in[10]; const in_t* s_ln2_g = (const in_t*)d_in[11];
  const in_t* s_ln2_b = (const in_t*)d_in[12]; const in_t* s_fc1_w = (const in_t*)d_in[13];
  const in_t* s_fc1_b = (const in_t*)d_in[14]; const in_t* s_fc2_w = (const in_t*)d_in[15];
  const in_t* s_fc2_b = (const in_t*)d_in[16]; const in_t* s_nrm_g = (const in_t*)d_in[17];
  const in_t* s_nrm_b = (const in_t*)d_in[18];
  const in_t* t_ln1_g = (const in_t*)d_in[19]; const in_t* t_ln1_b = (const in_t*)d_in[20];
  const in_t* t_qkv_w = (const in_t*)d_in[21]; const in_t* t_out_w = (const in_t*)d_in[22];
  const in_t* t_out_b = (const in_t*)d_in[23]; const in_t* t_ln2_g = (const in_t*)d_in[24];
  const in_t* t_ln2_b = (const in_t*)d_in[25]; const in_t* t_fc1_w = (const in_t*)d_in[26];
  const in_t* t_fc1_b = (const in_t*)d_in[27]; const in_t* t_fc2_w = (const in_t*)d_in[28];
  const in_t* t_fc2_b = (const in_t*)d_in[29]; const in_t* t_nrm_g = (const in_t*)d_in[30];
  const in_t* t_nrm_b = (const in_t*)d_in[31];
  const in_t* a_ln1_g = (const in_t*)d_in[32]; const in_t* a_ln1_b = (const in_t*)d_in[33];
  const in_t* a_qkv_w = (const in_t*)d_in[34]; const in_t* a_qkv_b = (const in_t*)d_in[35];
  const in_t* a_prj_w = (const in_t*)d_in[36]; const in_t* a_prj_b = (const in_t*)d_in[37];
  const in_t* a_ln2_g = (const in_t*)d_in[38]; const in_t* a_ln2_b = (const in_t*)d_in[39];
  const in_t* a_fc1_w = (const in_t*)d_in[40]; const in_t* a_fc1_b = (const in_t*)d_in[41];
  const in_t* a_fc2_w = (const in_t*)d_in[42]; const in_t* a_fc2_b = (const in_t*)d_in[43];
  const in_t* final_g = (const in_t*)d_in[44]; const in_t* final_b = (const in_t*)d_in[45];
  const in_t* h1_w = (const in_t*)d_in[46];    const in_t* h1_b = (const in_t*)d_in[47];
  const in_t* h2_w = (const in_t*)d_in[48];    const in_t* h2_b = (const in_t*)d_in[49];

  // ---- workspace partition (fp32 internal) ----
  float* ws = (float*)d_ws;
  size_t off = 0;
  auto alloc = [&](size_t nf) { size_t r = off; off += (nf + 63) & ~((size_t)63); return r; };
  size_t oX   = alloc((size_t)ROWS_*DMODEL);
  size_t oX2  = alloc((size_t)ROWS_*DMODEL);
  size_t oH   = alloc((size_t)ROWS_*DMODEL);
  size_t oQKV = alloc((size_t)ROWS_*1152);
  size_t oY   = alloc((size_t)ROWS_*384);
  size_t oFF  = alloc((size_t)ROWS_*768);
  size_t oA0  = alloc((size_t)480*NTOK);
  size_t oSB  = alloc((size_t)BT_*196);
  size_t oXC  = alloc((size_t)16*6*DMODEL);
  size_t oIDX = alloc((size_t)BT_*NTOK);       // ints
  if (ws_size < off*sizeof(float)) return;

  float* X   = ws + oX;
  float* X2  = ws + oX2;
  float* H   = ws + oH;
  float* QKV = ws + oQKV;
  float* Y   = ws + oY;
  float* FF  = ws + oFF;
  float* A0  = ws + oA0;
  float* SB  = ws + oSB;
  float* XC  = ws + oXC;
  int*   IDX = (int*)(ws + oIDX);

  auto gemm = [&](int epi, const float* A, const in_t* W, const in_t* bias,
                  const float* R, float* C, int M, int N, int K) {
    dim3 grid(N/64, (M+63)/64);
    if (epi == 0)      hipLaunchKernelGGL(gemm_k<0>, grid, dim3(256), 0, stream, A, W, bias, R, C, M, N, K);
    else if (epi == 1) hipLaunchKernelGGL(gemm_k<1>, grid, dim3(256), 0, stream, A, W, bias, R, C, M, N, K);
    else               hipLaunchKernelGGL(gemm_k<2>, grid, dim3(256), 0, stream, A, W, bias, R, C, M, N, K);
  };
  auto ln = [&](const float* xi, const in_t* g, const in_t* b, float* o, int rows) {
    hipLaunchKernelGGL(ln_k, dim3((rows+3)/4), dim3(256), 0, stream, xi, g, b, o, rows);
  };

  // ---- 1. patch embedding ----
  {
    int total = BT_*196*768;
    hipLaunchKernelGGL(patchify_k, dim3((total+255)/256), dim3(256), 0, stream, x_in, FF);
    gemm(0, FF, patch_w, patch_b, nullptr, Y, BT_*196, DMODEL, 768);
    int tot2 = BT_*NTOK*DMODEL;
    hipLaunchKernelGGL(assemble_k, dim3((tot2+255)/256), dim3(256), 0, stream, Y, space_tk, pos_emb, X);
  }

  const float sc64 = 0.125f;                   // 64^-0.5
  const float sc32 = 0.17677669529663687f;     // 32^-0.5

  // ---- 2. spatial transformer (2 layers, heads=6, dh=64) ----
  for (int i = 0; i < 2; ++i) {
    ln(X, s_ln1_g + (size_t)i*192, s_ln1_b + (size_t)i*192, H, ROWS_);
    gemm(0, H, s_qkv_w + (size_t)i*192*1152, nullptr, nullptr, QKV, ROWS_, 1152, 192);
    hipLaunchKernelGGL((attn2_k<64,8>), dim3(BT_*6), dim3(512), 0, stream, QKV, Y, (float*)nullptr, NTOK, 6, sc64);
    gemm(2, Y, s_out_w + (size_t)i*384*192, s_out_b + (size_t)i*192, X, X, ROWS_, 192, 384);
    ln(X, s_ln2_g + (size_t)i*192, s_ln2_b + (size_t)i*192, H, ROWS_);
    gemm(1, H, s_fc1_w + (size_t)i*192*768, s_fc1_b + (size_t)i*768, nullptr, FF, ROWS_, 768, 192);
    gemm(2, FF, s_fc2_w + (size_t)i*768*192, s_fc2_b + (size_t)i*192, X, X, ROWS_, 192, 768);
  }
  ln(X, s_nrm_g, s_nrm_b, X, ROWS_);

  // ---- 3. ATS blocks (12 layers, heads=6, dh=32) ----
  float* xa = X; float* xb = X2;
  for (int i = 0; i < 12; ++i) {
    ln(xa, a_ln1_g + (size_t)i*192, a_ln1_b + (size_t)i*192, H, ROWS_);
    gemm(0, H, a_qkv_w + (size_t)i*192*576, a_qkv_b + (size_t)i*576, nullptr, QKV, ROWS_, 576, 192);
    hipLaunchKernelGGL((attn2_k<32,4>), dim3(BT_*6), dim3(256), 0, stream, QKV, Y, A0, NTOK, 6, sc32);
    gemm(0, Y, a_prj_w + (size_t)i*192*192, a_prj_b + (size_t)i*192, nullptr, H, ROWS_, 192, 192);
    hipLaunchKernelGGL(score_k, dim3(BT_), dim3(256), 0, stream, A0, QKV, SB);
    hipLaunchKernelGGL(sample_k, dim3(BT_), dim3(256), 0, stream, SB, IDX);
    {
      int tot = BT_*NTOK*DMODEL;
      hipLaunchKernelGGL(gather_k, dim3((tot+255)/256), dim3(256), 0, stream, xa, H, IDX, xb);
    }
    ln(xb, a_ln2_g + (size_t)i*192, a_ln2_b + (size_t)i*192, H, ROWS_);
    gemm(1, H, a_fc1_w + (size_t)i*192*768, a_fc1_b + (size_t)i*768, nullptr, FF, ROWS_, 768, 192);
    gemm(2, FF, a_fc2_w + (size_t)i*768*192, a_fc2_b + (size_t)i*192, xb, xb, ROWS_, 192, 768);
    float* tmp = xa; xa = xb; xb = tmp;
  }

  // ---- 4. temporal transformer (3 layers on [16,6,192]) ----
  {
    int tot = 16*6*DMODEL;
    hipLaunchKernelGGL(build_xc_k, dim3((tot+255)/256), dim3(256), 0, stream, xa, temp_tk, XC);
  }
  const int MT = 16*6;
  for (int i = 0; i < 3; ++i) {
    ln(XC, t_ln1_g + (size_t)i*192, t_ln1_b + (size_t)i*192, H, MT);
    gemm(0, H, t_qkv_w + (size_t)i*192*1152, nullptr, nullptr, QKV, MT, 1152, 192);
    hipLaunchKernelGGL((attn2_k<64,8>), dim3(16*6), dim3(512), 0, stream, QKV, Y, (float*)nullptr, 6, 6, sc64);
    gemm(2, Y, t_out_w + (size_t)i*384*192, t_out_b + (size_t)i*192, XC, XC, MT, 192, 384);
    ln(XC, t_ln2_g + (size_t)i*192, t_ln2_b + (size_t)i*192, H, MT);
    gemm(1, H, t_fc1_w + (size_t)i*192*768, t_fc1_b + (size_t)i*768, nullptr, FF, MT, 768, 192);
    gemm(2, FF, t_fc2_w + (size_t)i*768*192, t_fc2_b + (size_t)i*192, XC, XC, MT, 192, 768);
  }
  ln(XC, t_nrm_g, t_nrm_b, XC, MT);

  // ---- 5. maxpool + final LN + head ----
  hipLaunchKernelGGL(head_k, dim3(16), dim3(256), 0, stream, XC, final_g, final_b,
                     h1_w, h1_b, h2_w, h2_b, (out_t*)d_out);
}